// Round 1
// baseline (60.902 us; speedup 1.0000x reference)
//
#include <hip/hip_runtime.h>

#define DT (1.0f / 120.0f)

struct M2 { float a00, a01, a10, a11; };

__device__ __forceinline__ M2 mmul(const M2& x, const M2& y) {
    // row-vector convention: v@(X*Y) = (v@X)@Y
    M2 r;
    r.a00 = x.a00 * y.a00 + x.a01 * y.a10;
    r.a01 = x.a00 * y.a01 + x.a01 * y.a11;
    r.a10 = x.a10 * y.a00 + x.a11 * y.a10;
    r.a11 = x.a10 * y.a01 + x.a11 * y.a11;
    return r;
}

__device__ __forceinline__ float2 vmul(float2 v, const M2& m) {
    return make_float2(v.x * m.a00 + v.y * m.a10,
                       v.x * m.a01 + v.y * m.a11);
}

// One block per batch row. BLOCK threads x C steps each = BLOCK*C steps/tile.
// Linear-recurrence parallel scan: X_t = X_{t-1} @ A + u_t @ W.
template <int C, int BLOCK>
__global__ __launch_bounds__(BLOCK) void spring_scan(
    const float* __restrict__ u, const float* __restrict__ x0,
    const float* __restrict__ k_w, const float* __restrict__ b_w,
    const float* __restrict__ im, const float* __restrict__ imask,
    float* __restrict__ out, int T)
{
    static_assert(C == 16, "squaring count below assumes C==16");
    constexpr int NW = BLOCK / 64;

    const int brow = blockIdx.x;
    const int tid  = threadIdx.x;
    const int lane = tid & 63;
    const int wid  = tid >> 6;

    const float k  = fabsf(k_w[0]);
    const float bd = fabsf(b_w[0]);
    const float W00 = im[0] * imask[0] * DT, W01 = im[1] * imask[1] * DT;
    const float W10 = im[2] * imask[2] * DT, W11 = im[3] * imask[3] * DT;

    // x_new = x + v*DT ; v_new = -k*DT*x + (1-b*DT)*v   (row-vec right-mul)
    M2 A = { 1.0f, -k * DT, DT, 1.0f - bd * DT };

    // P[s] = A^(C * 2^s);  P[0] = A^16 via 4 squarings; P[6] = A^1024
    M2 P[7];
    {
        M2 t = A;
        #pragma unroll
        for (int i = 0; i < 4; ++i) t = mmul(t, t);
        P[0] = t;
        #pragma unroll
        for (int s = 1; s < 7; ++s) P[s] = mmul(P[s - 1], P[s - 1]);
    }
    // Mlane = A^(C*lane) from bits of lane (powers of A commute)
    M2 Mlane = { 1.f, 0.f, 0.f, 1.f };
    #pragma unroll
    for (int s = 0; s < 6; ++s)
        if ((lane >> s) & 1) Mlane = mmul(Mlane, P[s]);

    __shared__ float2 lds_tot[NW];

    const long rowbase = (long)brow * T * 2;
    const float* urow = u + rowbase;
    float* orow = out + rowbase;

    float2 X_init = make_float2(x0[brow * 2 + 0], x0[brow * 2 + 1]);

    constexpr int STEPS = C * BLOCK;
    for (int t0 = 0; t0 < T; t0 += STEPS) {
        // ---- load this thread's C steps (128B contiguous) ----
        float4 uc[C / 2];
        const float4* up = (const float4*)(urow + (long)(t0 + tid * C) * 2);
        #pragma unroll
        for (int i = 0; i < C / 2; ++i) uc[i] = up[i];

        // c_t = u_t @ W
        float2 c[C];
        #pragma unroll
        for (int i = 0; i < C / 2; ++i) {
            c[2 * i + 0] = make_float2(uc[i].x * W00 + uc[i].y * W10,
                                       uc[i].x * W01 + uc[i].y * W11);
            c[2 * i + 1] = make_float2(uc[i].z * W00 + uc[i].w * W10,
                                       uc[i].z * W01 + uc[i].w * W11);
        }

        // ---- local zero-seeded contribution over C steps ----
        float2 v = make_float2(0.f, 0.f);
        #pragma unroll
        for (int i = 0; i < C; ++i) {
            v = vmul(v, A);
            v.x += c[i].x; v.y += c[i].y;
        }

        // ---- wave-level inclusive scan (64 lanes, 6 steps) ----
        #pragma unroll
        for (int s = 0; s < 6; ++s) {
            float px = __shfl_up(v.x, 1u << s, 64);
            float py = __shfl_up(v.y, 1u << s, 64);
            if (lane >= (1 << s)) {
                float2 pv = vmul(make_float2(px, py), P[s]);
                v.x = pv.x + v.x; v.y = pv.y + v.y;
            }
        }

        // ---- block-level: wave totals via LDS ----
        if (lane == 63) lds_tot[wid] = v;
        __syncthreads();

        // off = actual state at the start of this wave's 1024-step span
        float2 off = X_init;
        for (int w2 = 0; w2 < wid; ++w2) {
            off = vmul(off, P[6]);
            off.x += lds_tot[w2].x; off.y += lds_tot[w2].y;
        }

        // exclusive within-wave prefix
        float ex = __shfl_up(v.x, 1u, 64);
        float ey = __shfl_up(v.y, 1u, 64);
        float2 vex = (lane == 0) ? make_float2(0.f, 0.f) : make_float2(ex, ey);

        // start state for this thread's chunk
        float2 X = vmul(off, Mlane);
        X.x += vex.x; X.y += vex.y;

        // ---- replay C steps exactly in reference order, store ----
        float4 oc[C / 2];
        #pragma unroll
        for (int i = 0; i < C; ++i) {
            X = vmul(X, A);
            X.x += c[i].x; X.y += c[i].y;
            if (i & 1) { oc[i / 2].z = X.x; oc[i / 2].w = X.y; }
            else       { oc[i / 2].x = X.x; oc[i / 2].y = X.y; }
        }
        float4* op = (float4*)(orow + (long)(t0 + tid * C) * 2);
        #pragma unroll
        for (int i = 0; i < C / 2; ++i) op[i] = oc[i];

        // ---- carry state to next tile (only if multi-tile) ----
        if (t0 + STEPS < T) {
            float2 fin = X_init;
            #pragma unroll
            for (int w2 = 0; w2 < NW; ++w2) {
                fin = vmul(fin, P[6]);
                fin.x += lds_tot[w2].x; fin.y += lds_tot[w2].y;
            }
            X_init = fin;
            __syncthreads();  // lds_tot reused next tile
        }
    }
}

extern "C" void kernel_launch(void* const* d_in, const int* in_sizes, int n_in,
                              void* d_out, int out_size, void* d_ws, size_t ws_size,
                              hipStream_t stream) {
    const float* u     = (const float*)d_in[0];
    const float* x0    = (const float*)d_in[1];
    const float* k_w   = (const float*)d_in[2];
    const float* b_w   = (const float*)d_in[3];
    const float* im    = (const float*)d_in[4];
    const float* imask = (const float*)d_in[5];
    float* out = (float*)d_out;

    const int B = in_sizes[1] / 2;        // x0 is (B,2)
    const int T = in_sizes[0] / (2 * B);  // u is (B,T,2)

    spring_scan<16, 256><<<B, 256, 0, stream>>>(u, x0, k_w, b_w, im, imask, out, T);
}

// Round 2
// 46.799 us; speedup vs baseline: 1.3014x; 1.3014x over previous
//
#include <hip/hip_runtime.h>
#include <stdint.h>

#define DT (1.0f / 120.0f)

struct M2 { float a00, a01, a10, a11; };

__device__ __forceinline__ M2 mmul(const M2& x, const M2& y) {
    // row-vector convention: v@(X*Y) = (v@X)@Y
    M2 r;
    r.a00 = x.a00 * y.a00 + x.a01 * y.a10;
    r.a01 = x.a00 * y.a01 + x.a01 * y.a11;
    r.a10 = x.a10 * y.a00 + x.a11 * y.a10;
    r.a11 = x.a10 * y.a01 + x.a11 * y.a11;
    return r;
}

__device__ __forceinline__ float2 vmul(float2 v, const M2& m) {
    return make_float2(v.x * m.a00 + v.y * m.a10,
                       v.x * m.a01 + v.y * m.a11);
}

// Async global->LDS, 16B per lane. LDS dest = wave-uniform base + lane*16.
#define GLOAD_LDS16(gp, lp) __builtin_amdgcn_global_load_lds(                 \
    (const __attribute__((address_space(1))) void*)(gp),                      \
    (__attribute__((address_space(3))) void*)(lp), 16, 0, 0)

// One block per batch row. Linear-recurrence parallel scan:
//   X_t = X_{t-1} @ A + u_t @ W
// All global traffic is coalesced via LDS bounce with slot swizzle
//   P(s) = s ^ ((s>>3)&7)   (involution on 16-B slot index, within 1KB window)
// so per-lane 128B chunk reads/writes hit LDS at its BW floor, and
// global load/store instructions stay fully coalesced.
template <int C, int BLOCK>
__global__ __launch_bounds__(BLOCK) void spring_scan(
    const float* __restrict__ u, const float* __restrict__ x0,
    const float* __restrict__ k_w, const float* __restrict__ b_w,
    const float* __restrict__ im, const float* __restrict__ imask,
    float* __restrict__ out, int T)
{
    static_assert(C == 16, "squaring count + swizzle assume C==16");
    constexpr int NW    = BLOCK / 64;
    constexpr int SLOTS = BLOCK * C / 2;   // float4 slots per tile (2048 = 32KB)
    constexpr int RNDS  = SLOTS / BLOCK;   // staging rounds (8)

    __shared__ float4 buf[SLOTS];
    __shared__ float2 lds_tot[NW];

    const int brow = blockIdx.x;
    const int tid  = threadIdx.x;
    const int lane = tid & 63;
    const int wid  = tid >> 6;

    const float k  = fabsf(k_w[0]);
    const float bd = fabsf(b_w[0]);
    const float W00 = im[0] * imask[0] * DT, W01 = im[1] * imask[1] * DT;
    const float W10 = im[2] * imask[2] * DT, W11 = im[3] * imask[3] * DT;

    // x_new = x + v*DT ; v_new = -k*DT*x + (1-b*DT)*v   (row-vec right-mul)
    M2 A = { 1.0f, -k * DT, DT, 1.0f - bd * DT };

    // P[s] = A^(C * 2^s);  P[0] = A^16 via 4 squarings; P[6] = A^1024
    M2 P[7];
    {
        M2 t = A;
        #pragma unroll
        for (int i = 0; i < 4; ++i) t = mmul(t, t);
        P[0] = t;
        #pragma unroll
        for (int s = 1; s < 7; ++s) P[s] = mmul(P[s - 1], P[s - 1]);
    }
    // Mlane = A^(C*lane) from bits of lane (powers of A commute)
    M2 Mlane = { 1.f, 0.f, 0.f, 1.f };
    #pragma unroll
    for (int s = 0; s < 6; ++s)
        if ((lane >> s) & 1) Mlane = mmul(Mlane, P[s]);

    const long rowbase = (long)brow * T * 2;
    const float4* urow4 = (const float4*)(u + rowbase);
    float4*       orow4 = (float4*)(out + rowbase);

    float2 X_init = make_float2(x0[brow * 2 + 0], x0[brow * 2 + 1]);

    constexpr int STEPS = C * BLOCK;
    for (int t0 = 0; t0 < T; t0 += STEPS) {
        const int tilebase = t0 / 2;  // float4 slot index of tile start

        // ---- stage u tile: coalesced global -> linear LDS, source pre-swizzled ----
        #pragma unroll
        for (int r = 0; r < RNDS; ++r) {
            const int p = r * BLOCK + tid;          // LDS slot this lane fills
            const int g = p ^ ((tid >> 3) & 7);     // P(p): global slot to fetch
            GLOAD_LDS16(urow4 + tilebase + g, &buf[r * BLOCK + (tid & ~63)]);
        }
        __syncthreads();   // drains vmcnt before barrier

        // ---- read own 128B chunk (swizzled ds_read_b128) + W transform ----
        float2 c[C];
        #pragma unroll
        for (int m = 0; m < C / 2; ++m) {
            float4 t = buf[tid * (C / 2) + (m ^ (tid & 7))];
            c[2 * m + 0] = make_float2(t.x * W00 + t.y * W10,
                                       t.x * W01 + t.y * W11);
            c[2 * m + 1] = make_float2(t.z * W00 + t.w * W10,
                                       t.z * W01 + t.w * W11);
        }

        // ---- local zero-seeded contribution over C steps ----
        float2 v = make_float2(0.f, 0.f);
        #pragma unroll
        for (int i = 0; i < C; ++i) {
            v = vmul(v, A);
            v.x += c[i].x; v.y += c[i].y;
        }

        // ---- wave-level inclusive scan (64 lanes, 6 steps) ----
        #pragma unroll
        for (int s = 0; s < 6; ++s) {
            float px = __shfl_up(v.x, 1u << s, 64);
            float py = __shfl_up(v.y, 1u << s, 64);
            if (lane >= (1 << s)) {
                float2 pv = vmul(make_float2(px, py), P[s]);
                v.x = pv.x + v.x; v.y = pv.y + v.y;
            }
        }

        // ---- block-level: wave totals via LDS ----
        if (lane == 63) lds_tot[wid] = v;
        __syncthreads();

        // off = actual state at the start of this wave's 1024-step span
        float2 off = X_init;
        for (int w2 = 0; w2 < wid; ++w2) {
            off = vmul(off, P[6]);
            off.x += lds_tot[w2].x; off.y += lds_tot[w2].y;
        }

        // exclusive within-wave prefix
        float ex = __shfl_up(v.x, 1u, 64);
        float ey = __shfl_up(v.y, 1u, 64);
        float2 vex = (lane == 0) ? make_float2(0.f, 0.f) : make_float2(ex, ey);

        // start state for this thread's chunk
        float2 X = vmul(off, Mlane);
        X.x += vex.x; X.y += vex.y;

        // ---- replay C steps in order; write pairs to own swizzled LDS slots ----
        #pragma unroll
        for (int m = 0; m < C / 2; ++m) {
            float4 o;
            X = vmul(X, A);
            X.x += c[2 * m + 0].x; X.y += c[2 * m + 0].y;
            o.x = X.x; o.y = X.y;
            X = vmul(X, A);
            X.x += c[2 * m + 1].x; X.y += c[2 * m + 1].y;
            o.z = X.x; o.w = X.y;
            buf[tid * (C / 2) + (m ^ (tid & 7))] = o;   // own region, no race
        }
        __syncthreads();

        // ---- coalesced store: linear LDS read -> swizzled global slot ----
        #pragma unroll
        for (int r = 0; r < RNDS; ++r) {
            const int p = r * BLOCK + tid;
            const int g = p ^ ((tid >> 3) & 7);
            orow4[tilebase + g] = buf[p];
        }

        // ---- carry state to next tile (only if multi-tile) ----
        if (t0 + STEPS < T) {
            float2 fin = X_init;
            #pragma unroll
            for (int w2 = 0; w2 < NW; ++w2) {
                fin = vmul(fin, P[6]);
                fin.x += lds_tot[w2].x; fin.y += lds_tot[w2].y;
            }
            X_init = fin;
            __syncthreads();  // buf + lds_tot reused next tile
        }
    }
}

extern "C" void kernel_launch(void* const* d_in, const int* in_sizes, int n_in,
                              void* d_out, int out_size, void* d_ws, size_t ws_size,
                              hipStream_t stream) {
    const float* u     = (const float*)d_in[0];
    const float* x0    = (const float*)d_in[1];
    const float* k_w   = (const float*)d_in[2];
    const float* b_w   = (const float*)d_in[3];
    const float* im    = (const float*)d_in[4];
    const float* imask = (const float*)d_in[5];
    float* out = (float*)d_out;

    const int B = in_sizes[1] / 2;        // x0 is (B,2)
    const int T = in_sizes[0] / (2 * B);  // u is (B,T,2)

    spring_scan<16, 256><<<B, 256, 0, stream>>>(u, x0, k_w, b_w, im, imask, out, T);
}